// Round 11
// baseline (684.444 us; speedup 1.0000x reference)
//
#include <hip/hip_runtime.h>
#include <hip/hip_bf16.h>

// out = x @ W^T + b + 2 * ((x@V) * codes) @ U^T
// M = 16384, N = 4096, K = 4096, rank = 8
//
// Round 11: occupancy experiment. 256x256 tile kept, BK 64->32 halves LDS to
// 64KB -> 2 blocks/CU (16 waves): sibling block's MFMA fills this block's
// barrier/vmcnt drains (m114 overlap). 2 barriers/tile, vmcnt(4) counted.
// Swizzle re-derived for 64B rows (4 slots, key=(row>>1)&3). Prep reverted
// to R8's proven form (R10's version regressed 100->155us).

typedef __bf16 bf16_t;
typedef __bf16 bf16x8 __attribute__((ext_vector_type(8)));
typedef float f32x4 __attribute__((ext_vector_type(4)));

#define M_TOT 16384
#define N_TOT 4096
#define K_TOT 4096
#define NT32 128  // K-tiles of 32

#define GLOAD_LDS16(gp, lp)                                                    \
  __builtin_amdgcn_global_load_lds(                                            \
      (const __attribute__((address_space(1))) void*)(gp),                     \
      (__attribute__((address_space(3))) void*)(lp), 16, 0, 0)

// ------------------------- fused prep: x->bf16 + g, and W->bf16 ------------
// R8-proven form: blocks [0,4096) x-part (4 rows each); [4096,12288) W-part.
__global__ void __launch_bounds__(256) prep_fused_kernel(
    const float* __restrict__ x, const float* __restrict__ codes,
    const float* __restrict__ V, const float* __restrict__ W,
    bf16_t* __restrict__ xbf, bf16_t* __restrict__ wbf,
    float* __restrict__ g) {
  const int tid = threadIdx.x;
  if (blockIdx.x >= 4096) {
    size_t i = ((size_t)(blockIdx.x - 4096) * 256 + tid) * 8;
    const float4* p = (const float4*)(W + i);
    float4 a = p[0], b = p[1];
    bf16x8 v;
    v[0] = (bf16_t)a.x; v[1] = (bf16_t)a.y; v[2] = (bf16_t)a.z; v[3] = (bf16_t)a.w;
    v[4] = (bf16_t)b.x; v[5] = (bf16_t)b.y; v[6] = (bf16_t)b.z; v[7] = (bf16_t)b.w;
    *(bf16x8*)(wbf + i) = v;
    return;
  }
  const int lane = tid & 63;
  const int wv = tid >> 6;
  const int m0 = blockIdx.x * 4;
  const int c0 = tid * 16;

  float xv[4][8];
#pragma unroll
  for (int rr = 0; rr < 4; ++rr)
#pragma unroll
    for (int r = 0; r < 8; ++r) xv[rr][r] = 0.f;

#pragma unroll
  for (int h = 0; h < 2; ++h) {
    const int cb = c0 + h * 8;
    float xr[4][8];
#pragma unroll
    for (int rr = 0; rr < 4; ++rr) {
      const float4* xp = (const float4*)(x + (size_t)(m0 + rr) * K_TOT + cb);
      float4 a0 = xp[0], a1 = xp[1];
      xr[rr][0] = a0.x; xr[rr][1] = a0.y; xr[rr][2] = a0.z; xr[rr][3] = a0.w;
      xr[rr][4] = a1.x; xr[rr][5] = a1.y; xr[rr][6] = a1.z; xr[rr][7] = a1.w;
      bf16x8 bv;
#pragma unroll
      for (int t = 0; t < 8; ++t) bv[t] = (bf16_t)xr[rr][t];
      *(bf16x8*)(xbf + (size_t)(m0 + rr) * K_TOT + cb) = bv;
    }
#pragma unroll
    for (int t = 0; t < 8; ++t) {
      const float4* vp = (const float4*)(V + (size_t)(cb + t) * 8);
      float4 v0 = vp[0], v1 = vp[1];
#pragma unroll
      for (int rr = 0; rr < 4; ++rr) {
        float xi = xr[rr][t];
        xv[rr][0] += xi * v0.x; xv[rr][1] += xi * v0.y;
        xv[rr][2] += xi * v0.z; xv[rr][3] += xi * v0.w;
        xv[rr][4] += xi * v1.x; xv[rr][5] += xi * v1.y;
        xv[rr][6] += xi * v1.z; xv[rr][7] += xi * v1.w;
      }
    }
  }

  __shared__ float red[4][4][8];
#pragma unroll
  for (int rr = 0; rr < 4; ++rr)
#pragma unroll
    for (int r = 0; r < 8; ++r) {
      float v = xv[rr][r];
      for (int s = 32; s > 0; s >>= 1) v += __shfl_down(v, s);
      if (lane == 0) red[wv][rr][r] = v;
    }
  __syncthreads();
  if (tid < 32) {
    int rr = tid >> 3, r = tid & 7;
    float tot = red[0][rr][r] + red[1][rr][r] + red[2][rr][r] + red[3][rr][r];
    int m = m0 + rr;
    g[m * 8 + r] = tot * codes[(size_t)m * 8 + r] * 2.0f;
  }
}

// ------------------------------------------------------------ 256^2 GEMM
#define BAR __builtin_amdgcn_s_barrier()
#define VMC4 asm volatile("s_waitcnt vmcnt(4)" ::: "memory")
#define VMC0 asm volatile("s_waitcnt vmcnt(0)" ::: "memory")

// Stage one full 256x32 tile (A or B) of K-tile KT into lds[DB*2+AB].
// 1024 chunks of 16B; chunk = i*512 + w*64 + lane (i=0,1). Linear LDS dest;
// pre-swizzled global k (slot = lane&3, key = (lane>>3)&3).
#define STAGE32(DB, AB, KT, SRC)                                               \
  {                                                                            \
    _Pragma("unroll") for (int i_ = 0; i_ < 2; ++i_) {                         \
      int row_ = i_ * 128 + w * 16 + (lane >> 2);                              \
      const bf16_t* gp_ = (SRC) + (size_t)row_ * K_TOT + (KT) * 32 + sgk32;    \
      GLOAD_LDS16(gp_, &lds[(DB) * 2 + (AB)][(i_ * 512 + w * 64 + lane) * 8]); \
    }                                                                          \
  }

// One K-tile = 1 MFMA window, 2 barriers. Cross-block TLP (2 blocks/CU)
// covers the drain stalls.
#define KT32(BUF, KT, S)                                                       \
  if (S) {                                                                     \
    STAGE32(BUF ^ 1, 0, (KT) + 1, aSrc);                                       \
    STAGE32(BUF ^ 1, 1, (KT) + 1, bSrc);                                       \
  }                                                                            \
  if (S) { VMC4; } else { VMC0; }                                              \
  BAR;                                                                         \
  _Pragma("unroll") for (int mi_ = 0; mi_ < 8; ++mi_)                          \
      aR[mi_] = *(const bf16x8*)&lds[(BUF) * 2][aoff + mi_ * 512];             \
  _Pragma("unroll") for (int nj_ = 0; nj_ < 4; ++nj_)                          \
      bR[nj_] = *(const bf16x8*)&lds[(BUF) * 2 + 1][boff + nj_ * 512];         \
  __builtin_amdgcn_s_setprio(1);                                               \
  _Pragma("unroll") for (int mi_ = 0; mi_ < 8; ++mi_)                          \
  _Pragma("unroll") for (int nj_ = 0; nj_ < 4; ++nj_)                          \
      acc[mi_][nj_] = __builtin_amdgcn_mfma_f32_16x16x32_bf16(                 \
          aR[mi_], bR[nj_], acc[mi_][nj_], 0, 0, 0);                           \
  __builtin_amdgcn_s_setprio(0);                                               \
  BAR;

__global__ void __launch_bounds__(512) gemm_kernel(
    const bf16_t* __restrict__ A,   // [16384][4096] bf16
    const bf16_t* __restrict__ Bm,  // [4096][4096] bf16
    const float* __restrict__ bias, const float* __restrict__ U,
    const float* __restrict__ g, float* __restrict__ out) {
  const int tid = threadIdx.x;
  const int lane = tid & 63;
  const int w = tid >> 6;  // 0..7
  const int wr = w >> 2;   // 0..1
  const int wc = w & 3;    // 0..3
  const int llo = lane & 15, lhi = lane >> 4;

  // XCD-bijective swizzle: nwg = 1024 (divisible by 8); bn fastest per XCD.
  int bid = blockIdx.x;
  int sw = (bid & 7) * 128 + (bid >> 3);
  const int bm = sw >> 4;  // 0..63
  const int bn = sw & 15;  // 0..15

  __shared__ __attribute__((aligned(128))) bf16_t lds[4][8192];  // 64 KiB

  const bf16_t* aSrc = A + (size_t)bm * 256 * K_TOT;
  const bf16_t* bSrc = Bm + (size_t)bn * 256 * K_TOT;

  // staging pre-swizzled global k-offset (elements)
  const int sgk32 = ((lane & 3) ^ ((lane >> 3) & 3)) * 8;

  // ds_read bases (elements): row*32 + swizzled-slot*8; slot key = (llo>>1)&3
  const int rslot = (lhi ^ ((llo >> 1) & 3)) * 8;
  const int aoff = (wr * 128 + llo) * 32 + rslot;  // + mi*512
  const int boff = (wc * 64 + llo) * 32 + rslot;   // + nj*512

  f32x4 acc[8][4] = {};
  bf16x8 aR[8], bR[4];

  // Prologue: stage tile0 (A+B = 4 loads). First KT32's stage of tile1
  // brings outstanding to 8; its vmcnt(4) drains exactly tile0's 4.
  STAGE32(0, 0, 0, aSrc);
  STAGE32(0, 1, 0, bSrc);

#pragma unroll 1
  for (int t = 0; t < NT32 - 2; t += 2) {
    KT32(0, t, 1);
    KT32(1, t + 1, 1);
  }
  KT32(0, NT32 - 2, 1);
  KT32(1, NT32 - 1, 0);

  // Epilogue: out = acc + bias[n] + dot8(g[m], U[n])
  const int n0 = bn * 256 + wc * 64;
  int nidx[4];
  float biasv[4];
  float Un[4][8];
#pragma unroll
  for (int nj = 0; nj < 4; ++nj) {
    int n = n0 + nj * 16 + llo;
    nidx[nj] = n;
    biasv[nj] = bias[n];
    const float4* up = (const float4*)(U + (size_t)n * 8);
    float4 u0 = up[0], u1 = up[1];
    Un[nj][0] = u0.x; Un[nj][1] = u0.y; Un[nj][2] = u0.z; Un[nj][3] = u0.w;
    Un[nj][4] = u1.x; Un[nj][5] = u1.y; Un[nj][6] = u1.z; Un[nj][7] = u1.w;
  }
#pragma unroll
  for (int mi = 0; mi < 8; ++mi) {
#pragma unroll
    for (int reg = 0; reg < 4; ++reg) {
      int m = bm * 256 + wr * 128 + mi * 16 + lhi * 4 + reg;
      const float4* gp = (const float4*)(g + m * 8);
      float4 g0 = gp[0], g1 = gp[1];
      float* orow = out + (size_t)m * N_TOT;
#pragma unroll
      for (int nj = 0; nj < 4; ++nj) {
        float lora = g0.x * Un[nj][0] + g0.y * Un[nj][1] + g0.z * Un[nj][2] +
                     g0.w * Un[nj][3] + g1.x * Un[nj][4] + g1.y * Un[nj][5] +
                     g1.z * Un[nj][6] + g1.w * Un[nj][7];
        orow[nidx[nj]] = acc[mi][nj][reg] + biasv[nj] + lora;
      }
    }
  }
}

// ------------------------------------------------- fallback (tiny ws): naive
__global__ void __launch_bounds__(256) naive_kernel(
    const float* __restrict__ x, const float* __restrict__ codes,
    const float* __restrict__ W, const float* __restrict__ bias,
    const float* __restrict__ U, const float* __restrict__ V,
    float* __restrict__ out) {
  int m = blockIdx.x >> 4;
  int n = ((blockIdx.x & 15) << 8) + threadIdx.x;
  const float* xr = x + (size_t)m * K_TOT;
  const float* wrow = W + (size_t)n * K_TOT;
  float acc = 0.f;
  float xv[8] = {0, 0, 0, 0, 0, 0, 0, 0};
  for (int k = 0; k < K_TOT; k += 4) {
    float4 xa = *(const float4*)(xr + k);
    float4 wa = *(const float4*)(wrow + k);
    acc += xa.x * wa.x + xa.y * wa.y + xa.z * wa.z + xa.w * wa.w;
    const float* xs = (const float*)&xa;
#pragma unroll
    for (int t = 0; t < 4; ++t) {
      const float* vrow = V + (size_t)(k + t) * 8;
      float xi = xs[t];
#pragma unroll
      for (int r = 0; r < 8; ++r) xv[r] += xi * vrow[r];
    }
  }
  float lora = 0.f;
#pragma unroll
  for (int r = 0; r < 8; ++r)
    lora += xv[r] * codes[(size_t)m * 8 + r] * U[(size_t)n * 8 + r];
  out[(size_t)m * N_TOT + n] = acc + bias[n] + 2.0f * lora;
}

extern "C" void kernel_launch(void* const* d_in, const int* in_sizes, int n_in,
                              void* d_out, int out_size, void* d_ws,
                              size_t ws_size, hipStream_t stream) {
  const float* x = (const float*)d_in[0];
  const float* codes = (const float*)d_in[1];
  const float* W = (const float*)d_in[2];
  const float* b = (const float*)d_in[3];
  const float* U = (const float*)d_in[4];
  const float* V = (const float*)d_in[5];
  float* out = (float*)d_out;

  const size_t xbf_bytes = (size_t)M_TOT * K_TOT * 2;  // 128 MiB
  const size_t wbf_bytes = (size_t)N_TOT * K_TOT * 2;  // 32 MiB
  const size_t g_bytes = (size_t)M_TOT * 8 * 4;        // 512 KiB

  if (ws_size >= xbf_bytes + wbf_bytes + g_bytes) {
    bf16_t* xbf = (bf16_t*)d_ws;
    bf16_t* wbf = (bf16_t*)((char*)d_ws + xbf_bytes);
    float* g = (float*)((char*)d_ws + xbf_bytes + wbf_bytes);
    hipLaunchKernelGGL(prep_fused_kernel, dim3(12288), dim3(256), 0, stream,
                       x, codes, V, W, xbf, wbf, g);
    hipLaunchKernelGGL(gemm_kernel, dim3(1024), dim3(512), 0, stream, xbf, wbf,
                       b, U, g, out);
  } else {
    hipLaunchKernelGGL(naive_kernel, dim3((M_TOT) * (N_TOT / 256)), dim3(256),
                       0, stream, x, codes, W, b, U, V, out);
  }
}

// Round 12
// 617.639 us; speedup vs baseline: 1.1082x; 1.1082x over previous
//
#include <hip/hip_runtime.h>
#include <hip/hip_bf16.h>

// out = x @ W^T + b + 2 * ((x@V) * codes) @ U^T
// M = 16384, N = 4096, K = 4096, rank = 8
//
// Round 12: revert to best-known R8 config (607us): R6 GEMM (470us, 53.5%
// MfmaUtil — optimum across schedule/shape/occupancy axes R2-R11) + R8 fused
// prep. One orthogonal tweak: non-temporal stores for `out` (write-once,
// never re-read) to keep the 256MB C-write out of L2 -> more panel reuse.

typedef __bf16 bf16_t;
typedef __bf16 bf16x8 __attribute__((ext_vector_type(8)));
typedef float f32x4 __attribute__((ext_vector_type(4)));

#define M_TOT 16384
#define N_TOT 4096
#define K_TOT 4096
#define NT 64  // K-tiles of 64

#define GLOAD_LDS16(gp, lp)                                                    \
  __builtin_amdgcn_global_load_lds(                                            \
      (const __attribute__((address_space(1))) void*)(gp),                     \
      (__attribute__((address_space(3))) void*)(lp), 16, 0, 0)

// ------------------------- fused prep: x->bf16 + g, and W->bf16 ------------
__global__ void __launch_bounds__(256) prep_fused_kernel(
    const float* __restrict__ x, const float* __restrict__ codes,
    const float* __restrict__ V, const float* __restrict__ W,
    bf16_t* __restrict__ xbf, bf16_t* __restrict__ wbf,
    float* __restrict__ g) {
  const int tid = threadIdx.x;
  if (blockIdx.x >= 4096) {
    // ---- W -> bf16 (blocks 4096..12287 cover 4096x4096 elems, 8/thread)
    size_t i = ((size_t)(blockIdx.x - 4096) * 256 + tid) * 8;
    const float4* p = (const float4*)(W + i);
    float4 a = p[0], b = p[1];
    bf16x8 v;
    v[0] = (bf16_t)a.x; v[1] = (bf16_t)a.y; v[2] = (bf16_t)a.z; v[3] = (bf16_t)a.w;
    v[4] = (bf16_t)b.x; v[5] = (bf16_t)b.y; v[6] = (bf16_t)b.z; v[7] = (bf16_t)b.w;
    *(bf16x8*)(wbf + i) = v;
    return;
  }
  // ---- x -> bf16 + g = 2*(x@V)*codes (blocks 0..4095, 4 rows each)
  const int lane = tid & 63;
  const int wv = tid >> 6;
  const int m0 = blockIdx.x * 4;
  const int c0 = tid * 16;

  float xv[4][8];
#pragma unroll
  for (int rr = 0; rr < 4; ++rr)
#pragma unroll
    for (int r = 0; r < 8; ++r) xv[rr][r] = 0.f;

#pragma unroll
  for (int h = 0; h < 2; ++h) {
    const int cb = c0 + h * 8;
    float xr[4][8];
#pragma unroll
    for (int rr = 0; rr < 4; ++rr) {
      const float4* xp = (const float4*)(x + (size_t)(m0 + rr) * K_TOT + cb);
      float4 a0 = xp[0], a1 = xp[1];
      xr[rr][0] = a0.x; xr[rr][1] = a0.y; xr[rr][2] = a0.z; xr[rr][3] = a0.w;
      xr[rr][4] = a1.x; xr[rr][5] = a1.y; xr[rr][6] = a1.z; xr[rr][7] = a1.w;
      bf16x8 bv;
#pragma unroll
      for (int t = 0; t < 8; ++t) bv[t] = (bf16_t)xr[rr][t];
      *(bf16x8*)(xbf + (size_t)(m0 + rr) * K_TOT + cb) = bv;
    }
#pragma unroll
    for (int t = 0; t < 8; ++t) {
      const float4* vp = (const float4*)(V + (size_t)(cb + t) * 8);
      float4 v0 = vp[0], v1 = vp[1];
#pragma unroll
      for (int rr = 0; rr < 4; ++rr) {
        float xi = xr[rr][t];
        xv[rr][0] += xi * v0.x; xv[rr][1] += xi * v0.y;
        xv[rr][2] += xi * v0.z; xv[rr][3] += xi * v0.w;
        xv[rr][4] += xi * v1.x; xv[rr][5] += xi * v1.y;
        xv[rr][6] += xi * v1.z; xv[rr][7] += xi * v1.w;
      }
    }
  }

  __shared__ float red[4][4][8];
#pragma unroll
  for (int rr = 0; rr < 4; ++rr)
#pragma unroll
    for (int r = 0; r < 8; ++r) {
      float v = xv[rr][r];
      for (int s = 32; s > 0; s >>= 1) v += __shfl_down(v, s);
      if (lane == 0) red[wv][rr][r] = v;
    }
  __syncthreads();
  if (tid < 32) {
    int rr = tid >> 3, r = tid & 7;
    float tot = red[0][rr][r] + red[1][rr][r] + red[2][rr][r] + red[3][rr][r];
    int m = m0 + rr;
    g[m * 8 + r] = tot * codes[(size_t)m * 8 + r] * 2.0f;
  }
}

// ------------------------------------------------------------ 256^2 GEMM
#define BAR __builtin_amdgcn_s_barrier()
#define VMC4 asm volatile("s_waitcnt vmcnt(4)" ::: "memory")
#define VMC0 asm volatile("s_waitcnt vmcnt(0)" ::: "memory")

// Stage one half-tile (128 rows x 64 cols) of K-tile KT into lds[DB*2+AB].
#define STAGE(DB, AB, HALF, KT, SRC)                                           \
  {                                                                            \
    _Pragma("unroll") for (int r_ = 0; r_ < 2; ++r_) {                         \
      int rowl_ = (HALF) * 128 + (r_ * 8 + w) * 8 + srow;                      \
      const bf16_t* gp_ = (SRC) + (size_t)rowl_ * K_TOT + (KT) * 64 + sgk;     \
      GLOAD_LDS16(gp_, &lds[(DB) * 2 + (AB)][rowl_ * 64 + sj * 8]);            \
    }                                                                          \
  }

#define READ_A(BUF, MI0, DST)                                                  \
  _Pragma("unroll") for (int mi_ = 0; mi_ < 4; ++mi_) {                        \
    DST[mi_][0] = *(const bf16x8*)&lds[(BUF) * 2][arow0 + ((MI0) + mi_) * 1024 + aslot0]; \
    DST[mi_][1] = *(const bf16x8*)&lds[(BUF) * 2][arow0 + ((MI0) + mi_) * 1024 + aslot1]; \
  }

#define READ_B(BUF, NJ0, DST)                                                  \
  _Pragma("unroll") for (int nj_ = 0; nj_ < 2; ++nj_) {                        \
    DST[nj_][0] = *(const bf16x8*)&lds[(BUF) * 2 + 1][brow0 + ((NJ0) + nj_) * 1024 + aslot0]; \
    DST[nj_][1] = *(const bf16x8*)&lds[(BUF) * 2 + 1][brow0 + ((NJ0) + nj_) * 1024 + aslot1]; \
  }

#define MFMA_Q(MI0, NJ0, ASRC, BSRC)                                           \
  __builtin_amdgcn_s_setprio(1);                                               \
  _Pragma("unroll") for (int mi_ = 0; mi_ < 4; ++mi_)                          \
  _Pragma("unroll") for (int nj_ = 0; nj_ < 2; ++nj_) {                        \
    acc[(MI0) + mi_][(NJ0) + nj_] = __builtin_amdgcn_mfma_f32_16x16x32_bf16(   \
        ASRC[mi_][0], BSRC[nj_][0], acc[(MI0) + mi_][(NJ0) + nj_], 0, 0, 0);   \
    acc[(MI0) + mi_][(NJ0) + nj_] = __builtin_amdgcn_mfma_f32_16x16x32_bf16(   \
        ASRC[mi_][1], BSRC[nj_][1], acc[(MI0) + mi_][(NJ0) + nj_], 0, 0, 0);   \
  }                                                                            \
  __builtin_amdgcn_s_setprio(0);

// One K-tile = 4 MFMA windows, 5 barriers (R6 structure, proven best):
//   pre-W0: stage Ah1(KT+1); vmcnt(4); BAR
//   W0: A0-3,B01 reads + MFMA(0,0) + B23 prefetch
//   W1: stage Bh0(KT+1) + MFMA(0,2) + A4-7 prefetch (aG)
//   W2: stage Bh1(KT+1) + MFMA(4,2)
//   W3: stage Ah0(KT+2) + MFMA(4,0)
#define KTILE(BUF, KT, S1, S2, VM)                                             \
  if (S1) STAGE(BUF ^ 1, 0, 1, (KT) + 1, aSrc);                                \
  if ((VM) == 4) { VMC4; } else { VMC0; }                                      \
  BAR;                                                                         \
  READ_A(BUF, 0, aF);                                                          \
  READ_B(BUF, 0, b01);                                                         \
  MFMA_Q(0, 0, aF, b01);                                                       \
  READ_B(BUF, 2, b23);                                                         \
  BAR;                                                                         \
  if (S1) STAGE(BUF ^ 1, 1, 0, (KT) + 1, bSrc);                                \
  MFMA_Q(0, 2, aF, b23);                                                       \
  READ_A(BUF, 4, aG);                                                          \
  BAR;                                                                         \
  if (S1) STAGE(BUF ^ 1, 1, 1, (KT) + 1, bSrc);                                \
  MFMA_Q(4, 2, aG, b23);                                                       \
  BAR;                                                                         \
  if (S2) STAGE(BUF, 0, 0, (KT) + 2, aSrc);                                    \
  MFMA_Q(4, 0, aG, b01);                                                       \
  BAR;

__global__ void __launch_bounds__(512) gemm_kernel(
    const bf16_t* __restrict__ A,   // [16384][4096] bf16
    const bf16_t* __restrict__ Bm,  // [4096][4096] bf16
    const float* __restrict__ bias, const float* __restrict__ U,
    const float* __restrict__ g, float* __restrict__ out) {
  const int tid = threadIdx.x;
  const int lane = tid & 63;
  const int w = tid >> 6;  // 0..7
  const int wr = w >> 2;   // 0..1
  const int wc = w & 3;    // 0..3
  const int llo = lane & 15, lhi = lane >> 4;

  // XCD-bijective swizzle: nwg = 1024 (divisible by 8); bn fastest per XCD.
  int bid = blockIdx.x;
  int sw = (bid & 7) * 128 + (bid >> 3);
  const int bm = sw >> 4;  // 0..63
  const int bn = sw & 15;  // 0..15

  __shared__ __attribute__((aligned(128))) bf16_t lds[4][16384];  // 128 KiB

  const bf16_t* aSrc = A + (size_t)bm * 256 * K_TOT;
  const bf16_t* bSrc = Bm + (size_t)bn * 256 * K_TOT;

  // staging per-thread constants (pre-swizzled global k-slot)
  const int srow = lane >> 3;        // row within 8-row chunk (= row & 7)
  const int sj = lane & 7;           // physical LDS slot (linear DMA dest)
  const int sgk = (sj ^ srow) * 8;   // global k-element offset

  // ds_read per-thread bases (element offsets into a 256x64 tile)
  const int xs = llo & 7;
  const int arow0 = (wr * 128 + llo) * 64;
  const int brow0 = (wc * 64 + llo) * 64;
  const int aslot0 = ((0 + lhi) ^ xs) * 8;  // kk=0
  const int aslot1 = ((4 + lhi) ^ xs) * 8;  // kk=1

  f32x4 acc[8][4] = {};
  bf16x8 aF[4][2], aG[4][2], b01[2][2], b23[2][2];

  // Prologue: tile0 all 4 halves + tile1 A-h0. First KTILE's pre-W0 stage
  // brings outstanding to 12; its vmcnt(4) drains exactly tile0's 8.
  STAGE(0, 0, 0, 0, aSrc);
  STAGE(0, 0, 1, 0, aSrc);
  STAGE(0, 1, 0, 0, bSrc);
  STAGE(0, 1, 1, 0, bSrc);
  STAGE(1, 0, 0, 1, aSrc);

#pragma unroll 1
  for (int t = 0; t < NT - 2; t += 2) {
    KTILE(0, t, 1, 1, 4);
    KTILE(1, t + 1, 1, 1, 4);
  }
  KTILE(0, NT - 2, 1, 0, 4);
  KTILE(1, NT - 1, 0, 0, 0);

  // Epilogue: out = acc + bias[n] + dot8(g[m], U[n]); non-temporal C-write.
  const int n0 = bn * 256 + wc * 64;
  int nidx[4];
  float biasv[4];
  float Un[4][8];
#pragma unroll
  for (int nj = 0; nj < 4; ++nj) {
    int n = n0 + nj * 16 + llo;
    nidx[nj] = n;
    biasv[nj] = bias[n];
    const float4* up = (const float4*)(U + (size_t)n * 8);
    float4 u0 = up[0], u1 = up[1];
    Un[nj][0] = u0.x; Un[nj][1] = u0.y; Un[nj][2] = u0.z; Un[nj][3] = u0.w;
    Un[nj][4] = u1.x; Un[nj][5] = u1.y; Un[nj][6] = u1.z; Un[nj][7] = u1.w;
  }
#pragma unroll
  for (int mi = 0; mi < 8; ++mi) {
#pragma unroll
    for (int reg = 0; reg < 4; ++reg) {
      int m = bm * 256 + wr * 128 + mi * 16 + lhi * 4 + reg;
      const float4* gp = (const float4*)(g + m * 8);
      float4 g0 = gp[0], g1 = gp[1];
      float* orow = out + (size_t)m * N_TOT;
#pragma unroll
      for (int nj = 0; nj < 4; ++nj) {
        float lora = g0.x * Un[nj][0] + g0.y * Un[nj][1] + g0.z * Un[nj][2] +
                     g0.w * Un[nj][3] + g1.x * Un[nj][4] + g1.y * Un[nj][5] +
                     g1.z * Un[nj][6] + g1.w * Un[nj][7];
        __builtin_nontemporal_store(acc[mi][nj][reg] + biasv[nj] + lora,
                                    &orow[nidx[nj]]);
      }
    }
  }
}

// ------------------------------------------------- fallback (tiny ws): naive
__global__ void __launch_bounds__(256) naive_kernel(
    const float* __restrict__ x, const float* __restrict__ codes,
    const float* __restrict__ W, const float* __restrict__ bias,
    const float* __restrict__ U, const float* __restrict__ V,
    float* __restrict__ out) {
  int m = blockIdx.x >> 4;
  int n = ((blockIdx.x & 15) << 8) + threadIdx.x;
  const float* xr = x + (size_t)m * K_TOT;
  const float* wrow = W + (size_t)n * K_TOT;
  float acc = 0.f;
  float xv[8] = {0, 0, 0, 0, 0, 0, 0, 0};
  for (int k = 0; k < K_TOT; k += 4) {
    float4 xa = *(const float4*)(xr + k);
    float4 wa = *(const float4*)(wrow + k);
    acc += xa.x * wa.x + xa.y * wa.y + xa.z * wa.z + xa.w * wa.w;
    const float* xs = (const float*)&xa;
#pragma unroll
    for (int t = 0; t < 4; ++t) {
      const float* vrow = V + (size_t)(k + t) * 8;
      float xi = xs[t];
#pragma unroll
      for (int r = 0; r < 8; ++r) xv[r] += xi * vrow[r];
    }
  }
  float lora = 0.f;
#pragma unroll
  for (int r = 0; r < 8; ++r)
    lora += xv[r] * codes[(size_t)m * 8 + r] * U[(size_t)n * 8 + r];
  out[(size_t)m * N_TOT + n] = acc + bias[n] + 2.0f * lora;
}

extern "C" void kernel_launch(void* const* d_in, const int* in_sizes, int n_in,
                              void* d_out, int out_size, void* d_ws,
                              size_t ws_size, hipStream_t stream) {
  const float* x = (const float*)d_in[0];
  const float* codes = (const float*)d_in[1];
  const float* W = (const float*)d_in[2];
  const float* b = (const float*)d_in[3];
  const float* U = (const float*)d_in[4];
  const float* V = (const float*)d_in[5];
  float* out = (float*)d_out;

  const size_t xbf_bytes = (size_t)M_TOT * K_TOT * 2;  // 128 MiB
  const size_t wbf_bytes = (size_t)N_TOT * K_TOT * 2;  // 32 MiB
  const size_t g_bytes = (size_t)M_TOT * 8 * 4;        // 512 KiB

  if (ws_size >= xbf_bytes + wbf_bytes + g_bytes) {
    bf16_t* xbf = (bf16_t*)d_ws;
    bf16_t* wbf = (bf16_t*)((char*)d_ws + xbf_bytes);
    float* g = (float*)((char*)d_ws + xbf_bytes + wbf_bytes);
    hipLaunchKernelGGL(prep_fused_kernel, dim3(12288), dim3(256), 0, stream,
                       x, codes, V, W, xbf, wbf, g);
    hipLaunchKernelGGL(gemm_kernel, dim3(1024), dim3(512), 0, stream, xbf, wbf,
                       b, U, g, out);
  } else {
    hipLaunchKernelGGL(naive_kernel, dim3((M_TOT) * (N_TOT / 256)), dim3(256),
                       0, stream, x, codes, W, b, U, V, out);
  }
}

// Round 13
// 606.172 us; speedup vs baseline: 1.1291x; 1.0189x over previous
//
#include <hip/hip_runtime.h>
#include <hip/hip_bf16.h>

// out = x @ W^T + b + 2 * ((x@V) * codes) @ U^T
// M = 16384, N = 4096, K = 4096, rank = 8
//
// Round 13 (final consolidation): exact best-known config = R8.
//  - GEMM: R6 structure (470us, 53.5% MfmaUtil, 0 bank conflicts). Optimum
//    across all tested axes: window forms (R2 490, R3 532, R4 537, R5 483,
//    R9 537), MFMA shape (R7 32x32: 594, VGPR-fenced), BK=32/occupancy
//    (R11: 570), nontemporal C (R12: +35MB WRITE, slower).
//  - Prep: fused x->bf16+g / W->bf16 (R8 form; R10's "coalescing" rewrite
//    regressed 100->155us).

typedef __bf16 bf16_t;
typedef __bf16 bf16x8 __attribute__((ext_vector_type(8)));
typedef float f32x4 __attribute__((ext_vector_type(4)));

#define M_TOT 16384
#define N_TOT 4096
#define K_TOT 4096
#define NT 64  // K-tiles of 64

#define GLOAD_LDS16(gp, lp)                                                    \
  __builtin_amdgcn_global_load_lds(                                            \
      (const __attribute__((address_space(1))) void*)(gp),                     \
      (__attribute__((address_space(3))) void*)(lp), 16, 0, 0)

// ------------------------- fused prep: x->bf16 + g, and W->bf16 ------------
__global__ void __launch_bounds__(256) prep_fused_kernel(
    const float* __restrict__ x, const float* __restrict__ codes,
    const float* __restrict__ V, const float* __restrict__ W,
    bf16_t* __restrict__ xbf, bf16_t* __restrict__ wbf,
    float* __restrict__ g) {
  const int tid = threadIdx.x;
  if (blockIdx.x >= 4096) {
    // ---- W -> bf16 (blocks 4096..12287 cover 4096x4096 elems, 8/thread)
    size_t i = ((size_t)(blockIdx.x - 4096) * 256 + tid) * 8;
    const float4* p = (const float4*)(W + i);
    float4 a = p[0], b = p[1];
    bf16x8 v;
    v[0] = (bf16_t)a.x; v[1] = (bf16_t)a.y; v[2] = (bf16_t)a.z; v[3] = (bf16_t)a.w;
    v[4] = (bf16_t)b.x; v[5] = (bf16_t)b.y; v[6] = (bf16_t)b.z; v[7] = (bf16_t)b.w;
    *(bf16x8*)(wbf + i) = v;
    return;
  }
  // ---- x -> bf16 + g = 2*(x@V)*codes (blocks 0..4095, 4 rows each)
  const int lane = tid & 63;
  const int wv = tid >> 6;
  const int m0 = blockIdx.x * 4;
  const int c0 = tid * 16;

  float xv[4][8];
#pragma unroll
  for (int rr = 0; rr < 4; ++rr)
#pragma unroll
    for (int r = 0; r < 8; ++r) xv[rr][r] = 0.f;

#pragma unroll
  for (int h = 0; h < 2; ++h) {
    const int cb = c0 + h * 8;
    float xr[4][8];
#pragma unroll
    for (int rr = 0; rr < 4; ++rr) {
      const float4* xp = (const float4*)(x + (size_t)(m0 + rr) * K_TOT + cb);
      float4 a0 = xp[0], a1 = xp[1];
      xr[rr][0] = a0.x; xr[rr][1] = a0.y; xr[rr][2] = a0.z; xr[rr][3] = a0.w;
      xr[rr][4] = a1.x; xr[rr][5] = a1.y; xr[rr][6] = a1.z; xr[rr][7] = a1.w;
      bf16x8 bv;
#pragma unroll
      for (int t = 0; t < 8; ++t) bv[t] = (bf16_t)xr[rr][t];
      *(bf16x8*)(xbf + (size_t)(m0 + rr) * K_TOT + cb) = bv;
    }
#pragma unroll
    for (int t = 0; t < 8; ++t) {
      const float4* vp = (const float4*)(V + (size_t)(cb + t) * 8);
      float4 v0 = vp[0], v1 = vp[1];
#pragma unroll
      for (int rr = 0; rr < 4; ++rr) {
        float xi = xr[rr][t];
        xv[rr][0] += xi * v0.x; xv[rr][1] += xi * v0.y;
        xv[rr][2] += xi * v0.z; xv[rr][3] += xi * v0.w;
        xv[rr][4] += xi * v1.x; xv[rr][5] += xi * v1.y;
        xv[rr][6] += xi * v1.z; xv[rr][7] += xi * v1.w;
      }
    }
  }

  __shared__ float red[4][4][8];
#pragma unroll
  for (int rr = 0; rr < 4; ++rr)
#pragma unroll
    for (int r = 0; r < 8; ++r) {
      float v = xv[rr][r];
      for (int s = 32; s > 0; s >>= 1) v += __shfl_down(v, s);
      if (lane == 0) red[wv][rr][r] = v;
    }
  __syncthreads();
  if (tid < 32) {
    int rr = tid >> 3, r = tid & 7;
    float tot = red[0][rr][r] + red[1][rr][r] + red[2][rr][r] + red[3][rr][r];
    int m = m0 + rr;
    g[m * 8 + r] = tot * codes[(size_t)m * 8 + r] * 2.0f;
  }
}

// ------------------------------------------------------------ 256^2 GEMM
#define BAR __builtin_amdgcn_s_barrier()
#define VMC4 asm volatile("s_waitcnt vmcnt(4)" ::: "memory")
#define VMC0 asm volatile("s_waitcnt vmcnt(0)" ::: "memory")

// Stage one half-tile (128 rows x 64 cols) of K-tile KT into lds[DB*2+AB].
#define STAGE(DB, AB, HALF, KT, SRC)                                           \
  {                                                                            \
    _Pragma("unroll") for (int r_ = 0; r_ < 2; ++r_) {                         \
      int rowl_ = (HALF) * 128 + (r_ * 8 + w) * 8 + srow;                      \
      const bf16_t* gp_ = (SRC) + (size_t)rowl_ * K_TOT + (KT) * 64 + sgk;     \
      GLOAD_LDS16(gp_, &lds[(DB) * 2 + (AB)][rowl_ * 64 + sj * 8]);            \
    }                                                                          \
  }

#define READ_A(BUF, MI0, DST)                                                  \
  _Pragma("unroll") for (int mi_ = 0; mi_ < 4; ++mi_) {                        \
    DST[mi_][0] = *(const bf16x8*)&lds[(BUF) * 2][arow0 + ((MI0) + mi_) * 1024 + aslot0]; \
    DST[mi_][1] = *(const bf16x8*)&lds[(BUF) * 2][arow0 + ((MI0) + mi_) * 1024 + aslot1]; \
  }

#define READ_B(BUF, NJ0, DST)                                                  \
  _Pragma("unroll") for (int nj_ = 0; nj_ < 2; ++nj_) {                        \
    DST[nj_][0] = *(const bf16x8*)&lds[(BUF) * 2 + 1][brow0 + ((NJ0) + nj_) * 1024 + aslot0]; \
    DST[nj_][1] = *(const bf16x8*)&lds[(BUF) * 2 + 1][brow0 + ((NJ0) + nj_) * 1024 + aslot1]; \
  }

#define MFMA_Q(MI0, NJ0, ASRC, BSRC)                                           \
  __builtin_amdgcn_s_setprio(1);                                               \
  _Pragma("unroll") for (int mi_ = 0; mi_ < 4; ++mi_)                          \
  _Pragma("unroll") for (int nj_ = 0; nj_ < 2; ++nj_) {                        \
    acc[(MI0) + mi_][(NJ0) + nj_] = __builtin_amdgcn_mfma_f32_16x16x32_bf16(   \
        ASRC[mi_][0], BSRC[nj_][0], acc[(MI0) + mi_][(NJ0) + nj_], 0, 0, 0);   \
    acc[(MI0) + mi_][(NJ0) + nj_] = __builtin_amdgcn_mfma_f32_16x16x32_bf16(   \
        ASRC[mi_][1], BSRC[nj_][1], acc[(MI0) + mi_][(NJ0) + nj_], 0, 0, 0);   \
  }                                                                            \
  __builtin_amdgcn_s_setprio(0);

// One K-tile = 4 MFMA windows, 5 barriers (R6 structure, proven best):
//   pre-W0: stage Ah1(KT+1); vmcnt(4); BAR
//   W0: A0-3,B01 reads + MFMA(0,0) + B23 prefetch
//   W1: stage Bh0(KT+1) + MFMA(0,2) + A4-7 prefetch (aG)
//   W2: stage Bh1(KT+1) + MFMA(4,2)
//   W3: stage Ah0(KT+2) + MFMA(4,0)
#define KTILE(BUF, KT, S1, S2, VM)                                             \
  if (S1) STAGE(BUF ^ 1, 0, 1, (KT) + 1, aSrc);                                \
  if ((VM) == 4) { VMC4; } else { VMC0; }                                      \
  BAR;                                                                         \
  READ_A(BUF, 0, aF);                                                          \
  READ_B(BUF, 0, b01);                                                         \
  MFMA_Q(0, 0, aF, b01);                                                       \
  READ_B(BUF, 2, b23);                                                         \
  BAR;                                                                         \
  if (S1) STAGE(BUF ^ 1, 1, 0, (KT) + 1, bSrc);                                \
  MFMA_Q(0, 2, aF, b23);                                                       \
  READ_A(BUF, 4, aG);                                                          \
  BAR;                                                                         \
  if (S1) STAGE(BUF ^ 1, 1, 1, (KT) + 1, bSrc);                                \
  MFMA_Q(4, 2, aG, b23);                                                       \
  BAR;                                                                         \
  if (S2) STAGE(BUF, 0, 0, (KT) + 2, aSrc);                                    \
  MFMA_Q(4, 0, aG, b01);                                                       \
  BAR;

__global__ void __launch_bounds__(512) gemm_kernel(
    const bf16_t* __restrict__ A,   // [16384][4096] bf16
    const bf16_t* __restrict__ Bm,  // [4096][4096] bf16
    const float* __restrict__ bias, const float* __restrict__ U,
    const float* __restrict__ g, float* __restrict__ out) {
  const int tid = threadIdx.x;
  const int lane = tid & 63;
  const int w = tid >> 6;  // 0..7
  const int wr = w >> 2;   // 0..1
  const int wc = w & 3;    // 0..3
  const int llo = lane & 15, lhi = lane >> 4;

  // XCD-bijective swizzle: nwg = 1024 (divisible by 8); bn fastest per XCD.
  int bid = blockIdx.x;
  int sw = (bid & 7) * 128 + (bid >> 3);
  const int bm = sw >> 4;  // 0..63
  const int bn = sw & 15;  // 0..15

  __shared__ __attribute__((aligned(128))) bf16_t lds[4][16384];  // 128 KiB

  const bf16_t* aSrc = A + (size_t)bm * 256 * K_TOT;
  const bf16_t* bSrc = Bm + (size_t)bn * 256 * K_TOT;

  // staging per-thread constants (pre-swizzled global k-slot)
  const int srow = lane >> 3;        // row within 8-row chunk (= row & 7)
  const int sj = lane & 7;           // physical LDS slot (linear DMA dest)
  const int sgk = (sj ^ srow) * 8;   // global k-element offset

  // ds_read per-thread bases (element offsets into a 256x64 tile)
  const int xs = llo & 7;
  const int arow0 = (wr * 128 + llo) * 64;
  const int brow0 = (wc * 64 + llo) * 64;
  const int aslot0 = ((0 + lhi) ^ xs) * 8;  // kk=0
  const int aslot1 = ((4 + lhi) ^ xs) * 8;  // kk=1

  f32x4 acc[8][4] = {};
  bf16x8 aF[4][2], aG[4][2], b01[2][2], b23[2][2];

  // Prologue: tile0 all 4 halves + tile1 A-h0. First KTILE's pre-W0 stage
  // brings outstanding to 12; its vmcnt(4) drains exactly tile0's 8.
  STAGE(0, 0, 0, 0, aSrc);
  STAGE(0, 0, 1, 0, aSrc);
  STAGE(0, 1, 0, 0, bSrc);
  STAGE(0, 1, 1, 0, bSrc);
  STAGE(1, 0, 0, 1, aSrc);

#pragma unroll 1
  for (int t = 0; t < NT - 2; t += 2) {
    KTILE(0, t, 1, 1, 4);
    KTILE(1, t + 1, 1, 1, 4);
  }
  KTILE(0, NT - 2, 1, 0, 4);
  KTILE(1, NT - 1, 0, 0, 0);

  // Epilogue: out = acc + bias[n] + dot8(g[m], U[n])
  const int n0 = bn * 256 + wc * 64;
  int nidx[4];
  float biasv[4];
  float Un[4][8];
#pragma unroll
  for (int nj = 0; nj < 4; ++nj) {
    int n = n0 + nj * 16 + llo;
    nidx[nj] = n;
    biasv[nj] = bias[n];
    const float4* up = (const float4*)(U + (size_t)n * 8);
    float4 u0 = up[0], u1 = up[1];
    Un[nj][0] = u0.x; Un[nj][1] = u0.y; Un[nj][2] = u0.z; Un[nj][3] = u0.w;
    Un[nj][4] = u1.x; Un[nj][5] = u1.y; Un[nj][6] = u1.z; Un[nj][7] = u1.w;
  }
#pragma unroll
  for (int mi = 0; mi < 8; ++mi) {
#pragma unroll
    for (int reg = 0; reg < 4; ++reg) {
      int m = bm * 256 + wr * 128 + mi * 16 + lhi * 4 + reg;
      const float4* gp = (const float4*)(g + m * 8);
      float4 g0 = gp[0], g1 = gp[1];
      float* orow = out + (size_t)m * N_TOT;
#pragma unroll
      for (int nj = 0; nj < 4; ++nj) {
        float lora = g0.x * Un[nj][0] + g0.y * Un[nj][1] + g0.z * Un[nj][2] +
                     g0.w * Un[nj][3] + g1.x * Un[nj][4] + g1.y * Un[nj][5] +
                     g1.z * Un[nj][6] + g1.w * Un[nj][7];
        orow[nidx[nj]] = acc[mi][nj][reg] + biasv[nj] + lora;
      }
    }
  }
}

// ------------------------------------------------- fallback (tiny ws): naive
__global__ void __launch_bounds__(256) naive_kernel(
    const float* __restrict__ x, const float* __restrict__ codes,
    const float* __restrict__ W, const float* __restrict__ bias,
    const float* __restrict__ U, const float* __restrict__ V,
    float* __restrict__ out) {
  int m = blockIdx.x >> 4;
  int n = ((blockIdx.x & 15) << 8) + threadIdx.x;
  const float* xr = x + (size_t)m * K_TOT;
  const float* wrow = W + (size_t)n * K_TOT;
  float acc = 0.f;
  float xv[8] = {0, 0, 0, 0, 0, 0, 0, 0};
  for (int k = 0; k < K_TOT; k += 4) {
    float4 xa = *(const float4*)(xr + k);
    float4 wa = *(const float4*)(wrow + k);
    acc += xa.x * wa.x + xa.y * wa.y + xa.z * wa.z + xa.w * wa.w;
    const float* xs = (const float*)&xa;
#pragma unroll
    for (int t = 0; t < 4; ++t) {
      const float* vrow = V + (size_t)(k + t) * 8;
      float xi = xs[t];
#pragma unroll
      for (int r = 0; r < 8; ++r) xv[r] += xi * vrow[r];
    }
  }
  float lora = 0.f;
#pragma unroll
  for (int r = 0; r < 8; ++r)
    lora += xv[r] * codes[(size_t)m * 8 + r] * U[(size_t)n * 8 + r];
  out[(size_t)m * N_TOT + n] = acc + bias[n] + 2.0f * lora;
}

extern "C" void kernel_launch(void* const* d_in, const int* in_sizes, int n_in,
                              void* d_out, int out_size, void* d_ws,
                              size_t ws_size, hipStream_t stream) {
  const float* x = (const float*)d_in[0];
  const float* codes = (const float*)d_in[1];
  const float* W = (const float*)d_in[2];
  const float* b = (const float*)d_in[3];
  const float* U = (const float*)d_in[4];
  const float* V = (const float*)d_in[5];
  float* out = (float*)d_out;

  const size_t xbf_bytes = (size_t)M_TOT * K_TOT * 2;  // 128 MiB
  const size_t wbf_bytes = (size_t)N_TOT * K_TOT * 2;  // 32 MiB
  const size_t g_bytes = (size_t)M_TOT * 8 * 4;        // 512 KiB

  if (ws_size >= xbf_bytes + wbf_bytes + g_bytes) {
    bf16_t* xbf = (bf16_t*)d_ws;
    bf16_t* wbf = (bf16_t*)((char*)d_ws + xbf_bytes);
    float* g = (float*)((char*)d_ws + xbf_bytes + wbf_bytes);
    hipLaunchKernelGGL(prep_fused_kernel, dim3(12288), dim3(256), 0, stream,
                       x, codes, V, W, xbf, wbf, g);
    hipLaunchKernelGGL(gemm_kernel, dim3(1024), dim3(512), 0, stream, xbf, wbf,
                       b, U, g, out);
  } else {
    hipLaunchKernelGGL(naive_kernel, dim3((M_TOT) * (N_TOT / 256)), dim3(256),
                       0, stream, x, codes, W, b, U, V, out);
  }
}